// Round 1
// baseline (1392.978 us; speedup 1.0000x reference)
//
#include <hip/hip_runtime.h>
#include <hip/hip_bf16.h>

// ---------------------------------------------------------------------------
// 3-layer GAT forward (PyG GATConv semantics, eval mode) on MI355X.
// Layers: [129 -> 7x64] relu [448 -> 6x64] relu [384 -> 6x40]
// N=30000 nodes, E=480000 edges (+N self loops).
// Strategy: per layer  h = x@W (tiled fp32 GEMM)  ->  per-(node,head) logits
// -> dst-CSR edge softmax + gather-aggregate (one block per dst node).
// CSR rebuilt every launch (deterministic work; no cross-call state).
// ---------------------------------------------------------------------------

#define NFEAT 129

// ---------------- CSR build ----------------

__global__ __launch_bounds__(256) void init_cnt_k(int* __restrict__ cnt, int n) {
    int i = blockIdx.x * 256 + threadIdx.x;
    if (i < n) cnt[i] = 1;   // self-loop pre-counted
}

__global__ __launch_bounds__(256) void hist_k(const int* __restrict__ dst, int* __restrict__ cnt, int E) {
    int e = blockIdx.x * 256 + threadIdx.x;
    if (e < E) atomicAdd(&cnt[dst[e]], 1);
}

__global__ __launch_bounds__(1024) void scan_k(const int* __restrict__ cnt, int* __restrict__ row_ptr, int n) {
    __shared__ int part[1024];
    int tid = threadIdx.x;
    int per = (n + 1023) >> 10;
    int base = tid * per;
    int s = 0;
    for (int j = 0; j < per; ++j) {
        int idx = base + j;
        if (idx < n) s += cnt[idx];
    }
    part[tid] = s;
    __syncthreads();
    for (int off = 1; off < 1024; off <<= 1) {
        int v = 0;
        if (tid >= off) v = part[tid - off];
        __syncthreads();
        if (tid >= off) part[tid] += v;
        __syncthreads();
    }
    int run = (tid > 0) ? part[tid - 1] : 0;
    for (int j = 0; j < per; ++j) {
        int idx = base + j;
        if (idx < n) { row_ptr[idx] = run; run += cnt[idx]; }
    }
    if (tid == 0) row_ptr[n] = part[1023];
}

__global__ __launch_bounds__(256) void scatter_k(const int* __restrict__ src, const int* __restrict__ dst,
                                                 const int* __restrict__ row_ptr, int* __restrict__ fill,
                                                 int* __restrict__ col, int E, int n) {
    int e = blockIdx.x * 256 + threadIdx.x;
    if (e < E + n) {
        int s, d;
        if (e < E) { s = src[e]; d = dst[e]; }
        else       { s = d = e - E; }
        int pos = row_ptr[d] + atomicAdd(&fill[d], 1);
        col[pos] = s;
    }
}

// ---------------- GEMM: C[M,Nc] = A[M,K] @ B[K,Nc], fp32 ----------------

__global__ __launch_bounds__(256) void gemm_f32(const float* __restrict__ A,
                                                const float* __restrict__ B,
                                                float* __restrict__ C,
                                                int M, int Nc, int K) {
    const int BM = 64, BN = 64, BK = 16;
    __shared__ float As[BK][BM + 1];
    __shared__ float Bs[BK][BN + 1];
    int tid = threadIdx.x;
    int n0 = blockIdx.x * BN;
    int m0 = blockIdx.y * BM;
    int tx = tid & 15, ty = tid >> 4;
    float acc[4][4] = {};
    for (int k0 = 0; k0 < K; k0 += BK) {
        #pragma unroll
        for (int i = 0; i < 4; ++i) {
            int idx = tid + i * 256;
            int kk = idx & 15, mm = idx >> 4;
            int gm = m0 + mm, gk = k0 + kk;
            As[kk][mm] = (gm < M && gk < K) ? A[(size_t)gm * K + gk] : 0.f;
        }
        #pragma unroll
        for (int i = 0; i < 4; ++i) {
            int idx = tid + i * 256;
            int nn = idx & 63, kk = idx >> 6;
            int gn = n0 + nn, gk = k0 + kk;
            Bs[kk][nn] = (gn < Nc && gk < K) ? B[(size_t)gk * Nc + gn] : 0.f;
        }
        __syncthreads();
        #pragma unroll
        for (int kk = 0; kk < BK; ++kk) {
            float a[4], b[4];
            #pragma unroll
            for (int i = 0; i < 4; ++i) a[i] = As[kk][ty * 4 + i];
            #pragma unroll
            for (int j = 0; j < 4; ++j) b[j] = Bs[kk][tx * 4 + j];
            #pragma unroll
            for (int i = 0; i < 4; ++i)
                #pragma unroll
                for (int j = 0; j < 4; ++j) acc[i][j] += a[i] * b[j];
        }
        __syncthreads();
    }
    #pragma unroll
    for (int i = 0; i < 4; ++i) {
        int gm = m0 + ty * 4 + i;
        if (gm >= M) continue;
        #pragma unroll
        for (int j = 0; j < 4; ++j) {
            int gn = n0 + tx * 4 + j;
            if (gn < Nc) C[(size_t)gm * Nc + gn] = acc[i][j];
        }
    }
}

// ---------------- per-(node,head) attention logits ----------------
// alpha_s[i][h] = dot(h[i, h*C : h*C+C], a_s[h]);  same for alpha_d.
// One wave (64 lanes) per node.

template <int H, int C>
__global__ __launch_bounds__(64) void alphas_k(const float* __restrict__ hf,
                                               const float* __restrict__ a_s,
                                               const float* __restrict__ a_d,
                                               float* __restrict__ out_s,
                                               float* __restrict__ out_d, int n) {
    int i = blockIdx.x;
    if (i >= n) return;
    int lane = threadIdx.x;
    const float* row = hf + (size_t)i * (H * C);
    #pragma unroll
    for (int hh = 0; hh < H; ++hh) {
        float v = 0.f, ws = 0.f, wd = 0.f;
        if (lane < C) {
            v  = row[hh * C + lane];
            ws = a_s[hh * C + lane];
            wd = a_d[hh * C + lane];
        }
        float ps = v * ws, pd = v * wd;
        #pragma unroll
        for (int off = 32; off; off >>= 1) {
            ps += __shfl_xor(ps, off);
            pd += __shfl_xor(pd, off);
        }
        if (lane == 0) {
            out_s[(size_t)i * 8 + hh] = ps;
            out_d[(size_t)i * 8 + hh] = pd;
        }
    }
}

// ---------------- edge softmax + aggregate (one block per dst node) --------

template <int H, int C, bool RELU>
__global__ __launch_bounds__(256) void gat_agg(const float* __restrict__ hfeat,
                                               const float* __restrict__ as_,
                                               const float* __restrict__ ad_,
                                               const float* __restrict__ bias,
                                               const int* __restrict__ row_ptr,
                                               const int* __restrict__ col,
                                               float* __restrict__ out, int n) {
    constexpr int HC = H * C;
    constexpr int R = (HC + 255) / 256;
    int i = blockIdx.x;
    if (i >= n) return;
    int tid = threadIdx.x;
    __shared__ float ad_sh[8];
    __shared__ float m_sh[8];
    __shared__ float den_sh[8];
    __shared__ int   sbuf[64];
    __shared__ float wbuf[64][8];
    __shared__ float red_sh[4 * 8];
    if (tid < H) ad_sh[tid] = ad_[(size_t)i * 8 + tid];
    __syncthreads();
    int beg = row_ptr[i], end = row_ptr[i + 1];

    // pass 1: per-head max of leaky-relu(alpha_s[src] + alpha_d[i])
    float mloc[H];
    #pragma unroll
    for (int hh = 0; hh < H; ++hh) mloc[hh] = -1e30f;
    for (int e = beg + tid; e < end; e += 256) {
        int s = col[e];
        #pragma unroll
        for (int hh = 0; hh < H; ++hh) {
            float v = as_[(size_t)s * 8 + hh] + ad_sh[hh];
            v = v > 0.f ? v : 0.2f * v;
            mloc[hh] = fmaxf(mloc[hh], v);
        }
    }
    #pragma unroll
    for (int hh = 0; hh < H; ++hh) {
        #pragma unroll
        for (int off = 32; off; off >>= 1)
            mloc[hh] = fmaxf(mloc[hh], __shfl_xor(mloc[hh], off));
    }
    int wid = tid >> 6;
    if ((tid & 63) == 0) {
        #pragma unroll
        for (int hh = 0; hh < H; ++hh) red_sh[wid * 8 + hh] = mloc[hh];
    }
    __syncthreads();
    if (tid < H) {
        float m = red_sh[tid];
        #pragma unroll
        for (int w = 1; w < 4; ++w) m = fmaxf(m, red_sh[w * 8 + tid]);
        m_sh[tid] = m;
    }
    __syncthreads();

    // pass 2: exp weights (chunks of 64 edges in LDS) + feature aggregation
    float dpart[H];
    #pragma unroll
    for (int hh = 0; hh < H; ++hh) dpart[hh] = 0.f;
    float acc[R];
    #pragma unroll
    for (int r = 0; r < R; ++r) acc[r] = 0.f;

    for (int base = beg; base < end; base += 64) {
        int n_e = min(64, end - base);
        if (tid < n_e) {
            int s = col[base + tid];
            sbuf[tid] = s;
            #pragma unroll
            for (int hh = 0; hh < H; ++hh) {
                float v = as_[(size_t)s * 8 + hh] + ad_sh[hh];
                v = v > 0.f ? v : 0.2f * v;
                float ex = expf(v - m_sh[hh]);
                wbuf[tid][hh] = ex;
                dpart[hh] += ex;
            }
        }
        __syncthreads();
        for (int j = 0; j < n_e; ++j) {
            int s = sbuf[j];
            const float* hrow = hfeat + (size_t)s * HC;
            #pragma unroll
            for (int r = 0; r < R; ++r) {
                int c = tid + r * 256;
                if ((HC % 256 == 0) || c < HC)
                    acc[r] += wbuf[j][c / C] * hrow[c];
            }
        }
        __syncthreads();
    }

    // reduce denom (only wave 0 contributed)
    if (tid < 64) {
        #pragma unroll
        for (int hh = 0; hh < H; ++hh) {
            #pragma unroll
            for (int off = 32; off; off >>= 1)
                dpart[hh] += __shfl_xor(dpart[hh], off);
        }
        if (tid == 0) {
            #pragma unroll
            for (int hh = 0; hh < H; ++hh) den_sh[hh] = dpart[hh];
        }
    }
    __syncthreads();

    #pragma unroll
    for (int r = 0; r < R; ++r) {
        int c = tid + r * 256;
        if ((HC % 256 == 0) || c < HC) {
            float o = acc[r] / (den_sh[c / C] + 1e-16f) + bias[c];
            if (RELU) o = fmaxf(o, 0.f);
            out[(size_t)i * HC + c] = o;
        }
    }
}

// ---------------------------------------------------------------------------

extern "C" void kernel_launch(void* const* d_in, const int* in_sizes, int n_in,
                              void* d_out, int out_size, void* d_ws, size_t ws_size,
                              hipStream_t stream) {
    const float* x   = (const float*)d_in[0];
    const int*   ei  = (const int*)d_in[1];
    const float* W1  = (const float*)d_in[2];
    const float* a1s = (const float*)d_in[3];
    const float* a1d = (const float*)d_in[4];
    const float* b1  = (const float*)d_in[5];
    const float* W2  = (const float*)d_in[6];
    const float* a2s = (const float*)d_in[7];
    const float* a2d = (const float*)d_in[8];
    const float* b2  = (const float*)d_in[9];
    const float* W3  = (const float*)d_in[10];
    const float* a3s = (const float*)d_in[11];
    const float* a3d = (const float*)d_in[12];
    const float* b3  = (const float*)d_in[13];
    float* out = (float*)d_out;

    const int Nn = in_sizes[0] / NFEAT;   // 30000
    const int E  = in_sizes[1] / 2;       // 480000
    const int* srcp = ei;
    const int* dstp = ei + E;

    // workspace carve-up
    char* ws = (char*)d_ws;
    size_t off = 0;
    auto carve = [&](size_t bytes) -> char* {
        char* p = ws + off;
        off += (bytes + 255) & ~(size_t)255;
        return p;
    };
    float* bufA   = (float*)carve((size_t)Nn * 448 * 4);
    float* bufB   = (float*)carve((size_t)Nn * 448 * 4);
    float* asb    = (float*)carve((size_t)Nn * 8 * 4);
    float* adb    = (float*)carve((size_t)Nn * 8 * 4);
    int*   row_ptr= (int*)  carve((size_t)(Nn + 1) * 4);
    int*   cnt    = (int*)  carve((size_t)Nn * 4);
    int*   col    = (int*)  carve((size_t)(E + Nn) * 4);
    (void)ws_size;

    // ---- build dst-CSR (with self loops) ----
    init_cnt_k<<<(Nn + 255) / 256, 256, 0, stream>>>(cnt, Nn);
    hist_k<<<(E + 255) / 256, 256, 0, stream>>>(dstp, cnt, E);
    scan_k<<<1, 1024, 0, stream>>>(cnt, row_ptr, Nn);
    hipMemsetAsync(cnt, 0, (size_t)Nn * 4, stream);
    scatter_k<<<(E + Nn + 255) / 256, 256, 0, stream>>>(srcp, dstp, row_ptr, cnt, col, E, Nn);

    // ---- layer 1: 129 -> 7x64 ----
    {
        dim3 g((448 + 63) / 64, (Nn + 63) / 64);
        gemm_f32<<<g, 256, 0, stream>>>(x, W1, bufA, Nn, 448, NFEAT);
        alphas_k<7, 64><<<Nn, 64, 0, stream>>>(bufA, a1s, a1d, asb, adb, Nn);
        gat_agg<7, 64, true><<<Nn, 256, 0, stream>>>(bufA, asb, adb, b1, row_ptr, col, bufB, Nn);
    }
    // ---- layer 2: 448 -> 6x64 ----
    {
        dim3 g((384 + 63) / 64, (Nn + 63) / 64);
        gemm_f32<<<g, 256, 0, stream>>>(bufB, W2, bufA, Nn, 384, 448);
        alphas_k<6, 64><<<Nn, 64, 0, stream>>>(bufA, a2s, a2d, asb, adb, Nn);
        gat_agg<6, 64, true><<<Nn, 256, 0, stream>>>(bufA, asb, adb, b2, row_ptr, col, bufB, Nn);
    }
    // ---- layer 3: 384 -> 6x40 ----
    {
        dim3 g((240 + 63) / 64, (Nn + 63) / 64);
        gemm_f32<<<g, 256, 0, stream>>>(bufB, W3, bufA, Nn, 240, 384);
        alphas_k<6, 40><<<Nn, 64, 0, stream>>>(bufA, a3s, a3d, asb, adb, Nn);
        gat_agg<6, 40, false><<<Nn, 256, 0, stream>>>(bufA, asb, adb, b3, row_ptr, col, out, Nn);
    }
}

// Round 2
// 712.359 us; speedup vs baseline: 1.9554x; 1.9554x over previous
//
#include <hip/hip_runtime.h>
#include <hip/hip_bf16.h>

// ---------------------------------------------------------------------------
// 3-layer GAT forward (PyG GATConv, eval) on MI355X.
// GEMMs via bf16 hi/lo split MFMA (3 products, ~fp32 accuracy).
// Edge softmax+aggregate: barrier-free edge loop, float4 gathers, 2 edges in
// flight, no max pass (logits are O(10), exp safe in fp32).
// ---------------------------------------------------------------------------

#define NFEAT 129

typedef __attribute__((ext_vector_type(8))) short short8v;
typedef __attribute__((ext_vector_type(8))) __bf16 bf16x8;
typedef __attribute__((ext_vector_type(4))) float f32x4;

union FragU { short8v s; bf16x8 b; };

__device__ inline unsigned short f2bf(float x) {
    unsigned u = __builtin_bit_cast(unsigned, x);
    unsigned r = (u + 0x7fffu + ((u >> 16) & 1u)) >> 16;
    return (unsigned short)r;
}
__device__ inline float bf2f(unsigned short b) {
    unsigned u = ((unsigned)b) << 16;
    return __builtin_bit_cast(float, u);
}

// ---------------- CSR build ----------------

__global__ __launch_bounds__(256) void init_cnt_k(int* __restrict__ cnt, int n) {
    int i = blockIdx.x * 256 + threadIdx.x;
    if (i < n) cnt[i] = 1;   // self-loop pre-counted
}

__global__ __launch_bounds__(256) void hist_k(const int* __restrict__ dst, int* __restrict__ cnt, int E) {
    int e = blockIdx.x * 256 + threadIdx.x;
    if (e < E) atomicAdd(&cnt[dst[e]], 1);
}

__global__ __launch_bounds__(1024) void scan_k(const int* __restrict__ cnt, int* __restrict__ row_ptr, int n) {
    __shared__ int part[1024];
    int tid = threadIdx.x;
    int per = (n + 1023) >> 10;
    int base = tid * per;
    int s = 0;
    for (int j = 0; j < per; ++j) {
        int idx = base + j;
        if (idx < n) s += cnt[idx];
    }
    part[tid] = s;
    __syncthreads();
    for (int off = 1; off < 1024; off <<= 1) {
        int v = 0;
        if (tid >= off) v = part[tid - off];
        __syncthreads();
        if (tid >= off) part[tid] += v;
        __syncthreads();
    }
    int run = (tid > 0) ? part[tid - 1] : 0;
    for (int j = 0; j < per; ++j) {
        int idx = base + j;
        if (idx < n) { row_ptr[idx] = run; run += cnt[idx]; }
    }
    if (tid == 0) row_ptr[n] = part[1023];
}

__global__ __launch_bounds__(256) void scatter_k(const int* __restrict__ src, const int* __restrict__ dst,
                                                 const int* __restrict__ row_ptr, int* __restrict__ fill,
                                                 int* __restrict__ col, int E, int n) {
    int e = blockIdx.x * 256 + threadIdx.x;
    if (e < E + n) {
        int s, d;
        if (e < E) { s = src[e]; d = dst[e]; }
        else       { s = d = e - E; }
        int pos = row_ptr[d] + atomicAdd(&fill[d], 1);
        col[pos] = s;
    }
}

// ---------------- input split kernels (fp32 -> bf16 hi/lo, K-padded) -------

__global__ __launch_bounds__(256) void xsplit_k(const float* __restrict__ in,
                                                unsigned short* __restrict__ hi,
                                                unsigned short* __restrict__ lo,
                                                int M, int K, int Kp) {
    int idx = blockIdx.x * 256 + threadIdx.x;
    if (idx >= M * Kp) return;
    int m = idx / Kp, k = idx - m * Kp;
    float v = (k < K) ? in[(size_t)m * K + k] : 0.f;
    unsigned short h = f2bf(v);
    hi[idx] = h;
    lo[idx] = f2bf(v - bf2f(h));
}

// W is [K][N] row-major; produce transposed padded Wt[nn][k], nn<Npad, k<Kp
__global__ __launch_bounds__(256) void wsplit_k(const float* __restrict__ W,
                                                unsigned short* __restrict__ hi,
                                                unsigned short* __restrict__ lo,
                                                int K, int N, int Npad, int Kp) {
    int idx = blockIdx.x * 256 + threadIdx.x;
    if (idx >= Npad * Kp) return;
    int nn = idx / Kp, k = idx - nn * Kp;
    float v = (nn < N && k < K) ? W[(size_t)k * N + nn] : 0.f;
    unsigned short h = f2bf(v);
    hi[idx] = h;
    lo[idx] = f2bf(v - bf2f(h));
}

// ---------------- MFMA split GEMM: C[M,Ncols] = A[M,Kp] @ Wt[N,Kp]^T -------
// Tile 128x64, BK=64. 4 waves (2m x 2n). 3 MFMAs per (hi,lo) frag pair.

__global__ __launch_bounds__(256) void gemm_split(
    const unsigned short* __restrict__ Ahi, const unsigned short* __restrict__ Alo,
    const unsigned short* __restrict__ Bhi, const unsigned short* __restrict__ Blo,
    float* __restrict__ C, int M, int Ncols, int Kp)
{
    __shared__ __align__(16) unsigned short sAh[128 * 64];
    __shared__ __align__(16) unsigned short sAl[128 * 64];
    __shared__ __align__(16) unsigned short sBh[64 * 64];
    __shared__ __align__(16) unsigned short sBl[64 * 64];
    const int tid = threadIdx.x;
    const int m0 = blockIdx.y * 128;
    const int n0 = blockIdx.x * 64;
    const int lane = tid & 63, wave = tid >> 6;
    const int wm = wave >> 1, wn = wave & 1;
    const int l15 = lane & 15, lg = lane >> 4;
    f32x4 acc[4][2] = {};

    for (int k0 = 0; k0 < Kp; k0 += 64) {
        // stage A tiles (128 rows x 64 k): 1024 16B chunks each (hi, lo)
        #pragma unroll
        for (int i = 0; i < 4; ++i) {
            int c = tid + i * 256;
            int r = c >> 3, slot = c & 7;
            int sidx = (r << 3) | (slot ^ (r & 7));
            short8v vh = {}, vl = {};
            if (m0 + r < M) {
                size_t ga = (size_t)(m0 + r) * Kp + k0 + slot * 8;
                vh = *(const short8v*)(Ahi + ga);
                vl = *(const short8v*)(Alo + ga);
            }
            ((short8v*)sAh)[sidx] = vh;
            ((short8v*)sAl)[sidx] = vl;
        }
        // stage B tiles (64 n-rows x 64 k): 512 chunks each
        #pragma unroll
        for (int i = 0; i < 2; ++i) {
            int c = tid + i * 256;
            int r = c >> 3, slot = c & 7;
            int sidx = (r << 3) | (slot ^ (r & 7));
            size_t ga = (size_t)(n0 + r) * Kp + k0 + slot * 8;
            ((short8v*)sBh)[sidx] = *(const short8v*)(Bhi + ga);
            ((short8v*)sBl)[sidx] = *(const short8v*)(Blo + ga);
        }
        __syncthreads();
        #pragma unroll
        for (int kh = 0; kh < 2; ++kh) {
            FragU ah[4], am[4], bh[2], bm[2];
            #pragma unroll
            for (int mf = 0; mf < 4; ++mf) {
                int r = wm * 64 + mf * 16 + l15;
                int slot = kh * 4 + lg;
                int idx = (r << 3) | (slot ^ (r & 7));
                ah[mf].s = ((const short8v*)sAh)[idx];
                am[mf].s = ((const short8v*)sAl)[idx];
            }
            #pragma unroll
            for (int nf = 0; nf < 2; ++nf) {
                int r = wn * 32 + nf * 16 + l15;
                int slot = kh * 4 + lg;
                int idx = (r << 3) | (slot ^ (r & 7));
                bh[nf].s = ((const short8v*)sBh)[idx];
                bm[nf].s = ((const short8v*)sBl)[idx];
            }
            #pragma unroll
            for (int mf = 0; mf < 4; ++mf) {
                #pragma unroll
                for (int nf = 0; nf < 2; ++nf) {
                    acc[mf][nf] = __builtin_amdgcn_mfma_f32_16x16x32_bf16(ah[mf].b, bh[nf].b, acc[mf][nf], 0, 0, 0);
                    acc[mf][nf] = __builtin_amdgcn_mfma_f32_16x16x32_bf16(ah[mf].b, bm[nf].b, acc[mf][nf], 0, 0, 0);
                    acc[mf][nf] = __builtin_amdgcn_mfma_f32_16x16x32_bf16(am[mf].b, bh[nf].b, acc[mf][nf], 0, 0, 0);
                }
            }
        }
        __syncthreads();
    }
    // epilogue: C/D layout col = lane&15, row = (lane>>4)*4 + reg
    #pragma unroll
    for (int mf = 0; mf < 4; ++mf) {
        #pragma unroll
        for (int nf = 0; nf < 2; ++nf) {
            int colg = n0 + wn * 32 + nf * 16 + l15;
            if (colg >= Ncols) continue;
            #pragma unroll
            for (int r = 0; r < 4; ++r) {
                int rowg = m0 + wm * 64 + mf * 16 + lg * 4 + r;
                if (rowg < M) C[(size_t)rowg * Ncols + colg] = acc[mf][nf][r];
            }
        }
    }
}

// ---------------- per-(node,head) attention logits ----------------

template <int H, int C>
__global__ __launch_bounds__(64) void alphas_k(const float* __restrict__ hf,
                                               const float* __restrict__ a_s,
                                               const float* __restrict__ a_d,
                                               float* __restrict__ out_s,
                                               float* __restrict__ out_d, int n) {
    int i = blockIdx.x;
    if (i >= n) return;
    int lane = threadIdx.x;
    const float* row = hf + (size_t)i * (H * C);
    #pragma unroll
    for (int hh = 0; hh < H; ++hh) {
        float v = 0.f, ws = 0.f, wd = 0.f;
        if (lane < C) {
            v  = row[hh * C + lane];
            ws = a_s[hh * C + lane];
            wd = a_d[hh * C + lane];
        }
        float ps = v * ws, pd = v * wd;
        #pragma unroll
        for (int off = 32; off; off >>= 1) {
            ps += __shfl_xor(ps, off);
            pd += __shfl_xor(pd, off);
        }
        if (lane == 0) {
            out_s[(size_t)i * 8 + hh] = ps;
            out_d[(size_t)i * 8 + hh] = pd;
        }
    }
}

// ---------------- edge softmax + aggregate ----------------
// Block = 256 threads = 2 groups of 128; group g handles edges beg+g, beg+g+2...
// Each active thread owns 4 consecutive channels (float4 gather). No barriers
// in the edge loop. No max subtraction (logits are O(10); exp safe in fp32).

template <int H, int C, bool RELU, bool SPLIT>
__global__ __launch_bounds__(256) void gat_agg2(
    const float* __restrict__ hfeat, const float* __restrict__ as_,
    const float* __restrict__ ad_, const float* __restrict__ bias,
    const int* __restrict__ row_ptr, const int* __restrict__ col,
    float* __restrict__ outf, unsigned short* __restrict__ ohi,
    unsigned short* __restrict__ olo, int n)
{
    constexpr int HC = H * C;
    constexpr int CH4 = HC / 4;
    int i = blockIdx.x;
    if (i >= n) return;
    int tid = threadIdx.x;
    __shared__ float ad_sh[8];
    __shared__ float den_sh[8];
    __shared__ __align__(16) float red[HC];
    if (tid < 8) den_sh[tid] = 0.f;
    if (tid < H) ad_sh[tid] = ad_[(size_t)i * 8 + tid];
    __syncthreads();
    const int beg = row_ptr[i], end = row_ptr[i + 1];
    const int g = tid >> 7;
    const int t = tid & 127;
    const bool act = t < CH4;
    const int h = (t * 4) / C;
    const bool lead = act && (((t * 4) % C) == 0);
    float a0 = 0.f, a1 = 0.f, a2 = 0.f, a3 = 0.f, dp = 0.f;
    if (act) {
        const float adh = ad_sh[h];
        for (int e = beg + g; e < end; e += 2) {
            int s = col[e];
            float al = as_[(size_t)s * 8 + h] + adh;
            al = al > 0.f ? al : 0.2f * al;
            float w = __expf(al);
            const float4 hv = *(const float4*)(hfeat + (size_t)s * HC + t * 4);
            a0 += w * hv.x; a1 += w * hv.y; a2 += w * hv.z; a3 += w * hv.w;
            if (lead) dp += w;
        }
    }
    if (lead) atomicAdd(&den_sh[h], dp);
    if (g == 1 && act) {
        float4 v; v.x = a0; v.y = a1; v.z = a2; v.w = a3;
        *(float4*)&red[t * 4] = v;
    }
    __syncthreads();
    if (g == 0 && act) {
        const float4 r4 = *(const float4*)&red[t * 4];
        const float d = den_sh[h] + 1e-16f;
        const float4 b4 = *(const float4*)(bias + t * 4);
        float o0 = (a0 + r4.x) / d + b4.x;
        float o1 = (a1 + r4.y) / d + b4.y;
        float o2 = (a2 + r4.z) / d + b4.z;
        float o3 = (a3 + r4.w) / d + b4.w;
        if (RELU) {
            o0 = fmaxf(o0, 0.f); o1 = fmaxf(o1, 0.f);
            o2 = fmaxf(o2, 0.f); o3 = fmaxf(o3, 0.f);
        }
        size_t base = (size_t)i * HC + t * 4;
        if constexpr (SPLIT) {
            ushort4 ph, pl;
            ph.x = f2bf(o0); pl.x = f2bf(o0 - bf2f(ph.x));
            ph.y = f2bf(o1); pl.y = f2bf(o1 - bf2f(ph.y));
            ph.z = f2bf(o2); pl.z = f2bf(o2 - bf2f(ph.z));
            ph.w = f2bf(o3); pl.w = f2bf(o3 - bf2f(ph.w));
            *(ushort4*)(ohi + base) = ph;
            *(ushort4*)(olo + base) = pl;
        } else {
            float4 o; o.x = o0; o.y = o1; o.z = o2; o.w = o3;
            *(float4*)(outf + base) = o;
        }
    }
}

// ---------------------------------------------------------------------------

extern "C" void kernel_launch(void* const* d_in, const int* in_sizes, int n_in,
                              void* d_out, int out_size, void* d_ws, size_t ws_size,
                              hipStream_t stream) {
    const float* x   = (const float*)d_in[0];
    const int*   ei  = (const int*)d_in[1];
    const float* W1  = (const float*)d_in[2];
    const float* a1s = (const float*)d_in[3];
    const float* a1d = (const float*)d_in[4];
    const float* b1  = (const float*)d_in[5];
    const float* W2  = (const float*)d_in[6];
    const float* a2s = (const float*)d_in[7];
    const float* a2d = (const float*)d_in[8];
    const float* b2  = (const float*)d_in[9];
    const float* W3  = (const float*)d_in[10];
    const float* a3s = (const float*)d_in[11];
    const float* a3d = (const float*)d_in[12];
    const float* b3  = (const float*)d_in[13];
    float* out = (float*)d_out;

    const int Nn = in_sizes[0] / NFEAT;   // 30000
    const int E  = in_sizes[1] / 2;       // 480000
    const int* srcp = ei;
    const int* dstp = ei + E;

    char* ws = (char*)d_ws;
    size_t off = 0;
    auto carve = [&](size_t bytes) -> char* {
        char* p = ws + off;
        off += (bytes + 255) & ~(size_t)255;
        return p;
    };
    float*          hbuf = (float*)         carve((size_t)Nn * 448 * 4);
    unsigned short* Xhi  = (unsigned short*)carve((size_t)Nn * 448 * 2);
    unsigned short* Xlo  = (unsigned short*)carve((size_t)Nn * 448 * 2);
    unsigned short* Wthi = (unsigned short*)carve((size_t)448 * 448 * 2);
    unsigned short* Wtlo = (unsigned short*)carve((size_t)448 * 448 * 2);
    float*          asb  = (float*)         carve((size_t)Nn * 8 * 4);
    float*          adb  = (float*)         carve((size_t)Nn * 8 * 4);
    int*          row_ptr= (int*)           carve((size_t)(Nn + 1) * 4);
    int*            cnt  = (int*)           carve((size_t)Nn * 4);
    int*            col  = (int*)           carve((size_t)(E + Nn) * 4);
    (void)ws_size;

    const int mblk = (Nn + 127) / 128;

    // ---- build dst-CSR (with self loops) ----
    init_cnt_k<<<(Nn + 255) / 256, 256, 0, stream>>>(cnt, Nn);
    hist_k<<<(E + 255) / 256, 256, 0, stream>>>(dstp, cnt, E);
    scan_k<<<1, 1024, 0, stream>>>(cnt, row_ptr, Nn);
    hipMemsetAsync(cnt, 0, (size_t)Nn * 4, stream);
    scatter_k<<<(E + Nn + 255) / 256, 256, 0, stream>>>(srcp, dstp, row_ptr, cnt, col, E, Nn);

    // ---- layer 1: 129 -> 7x64 (Kp=192) ----
    xsplit_k<<<((Nn * 192) + 255) / 256, 256, 0, stream>>>(x, Xhi, Xlo, Nn, NFEAT, 192);
    wsplit_k<<<((448 * 192) + 255) / 256, 256, 0, stream>>>(W1, Wthi, Wtlo, NFEAT, 448, 448, 192);
    gemm_split<<<dim3(7, mblk), 256, 0, stream>>>(Xhi, Xlo, Wthi, Wtlo, hbuf, Nn, 448, 192);
    alphas_k<7, 64><<<Nn, 64, 0, stream>>>(hbuf, a1s, a1d, asb, adb, Nn);
    gat_agg2<7, 64, true, true><<<Nn, 256, 0, stream>>>(hbuf, asb, adb, b1, row_ptr, col,
                                                        nullptr, Xhi, Xlo, Nn);
    // ---- layer 2: 448 -> 6x64 ----
    wsplit_k<<<((384 * 448) + 255) / 256, 256, 0, stream>>>(W2, Wthi, Wtlo, 448, 384, 384, 448);
    gemm_split<<<dim3(6, mblk), 256, 0, stream>>>(Xhi, Xlo, Wthi, Wtlo, hbuf, Nn, 384, 448);
    alphas_k<6, 64><<<Nn, 64, 0, stream>>>(hbuf, a2s, a2d, asb, adb, Nn);
    gat_agg2<6, 64, true, true><<<Nn, 256, 0, stream>>>(hbuf, asb, adb, b2, row_ptr, col,
                                                        nullptr, Xhi, Xlo, Nn);
    // ---- layer 3: 384 -> 6x40 (Npad=256) ----
    wsplit_k<<<((256 * 384) + 255) / 256, 256, 0, stream>>>(W3, Wthi, Wtlo, 384, 240, 256, 384);
    gemm_split<<<dim3(4, mblk), 256, 0, stream>>>(Xhi, Xlo, Wthi, Wtlo, hbuf, Nn, 240, 384);
    alphas_k<6, 40><<<Nn, 64, 0, stream>>>(hbuf, a3s, a3d, asb, adb, Nn);
    gat_agg2<6, 40, false, false><<<Nn, 256, 0, stream>>>(hbuf, asb, adb, b3, row_ptr, col,
                                                          out, nullptr, nullptr, Nn);
}

// Round 3
// 624.186 us; speedup vs baseline: 2.2317x; 1.1413x over previous
//
#include <hip/hip_runtime.h>
#include <hip/hip_bf16.h>

// ---------------------------------------------------------------------------
// 3-layer GAT forward (PyG GATConv, eval) on MI355X.
// GEMM: bf16 hi/lo split MFMA (3 products), 128x128 tile BK=32, fused
//       alpha_s/alpha_d epilogue (layers 1-2).
// Agg:  chunk-sliced (128 ch) barrier-free gather, chunk-major dispatch for
//       cache locality, 1 wave per (node,chunk), float2 lanes.
// ---------------------------------------------------------------------------

#define NFEAT 129
#define MPAD  30080   // 235 * 128

typedef __attribute__((ext_vector_type(8))) short short8v;
typedef __attribute__((ext_vector_type(8))) __bf16 bf16x8;
typedef __attribute__((ext_vector_type(4))) float f32x4;
typedef unsigned short u16;

union FragU { short8v s; bf16x8 b; };

__device__ inline u16 f2bf(float x) {
    unsigned u = __builtin_bit_cast(unsigned, x);
    unsigned r = (u + 0x7fffu + ((u >> 16) & 1u)) >> 16;
    return (u16)r;
}
__device__ inline float bf2f(u16 b) {
    unsigned u = ((unsigned)b) << 16;
    return __builtin_bit_cast(float, u);
}

// ---------------- CSR build ----------------

__global__ __launch_bounds__(256) void init_cnt_k(int* __restrict__ cnt, int n) {
    int i = blockIdx.x * 256 + threadIdx.x;
    if (i < n) cnt[i] = 1;   // self-loop pre-counted
}

__global__ __launch_bounds__(256) void hist_k(const int* __restrict__ dst, int* __restrict__ cnt, int E) {
    int e = blockIdx.x * 256 + threadIdx.x;
    if (e < E) atomicAdd(&cnt[dst[e]], 1);
}

__global__ __launch_bounds__(1024) void scan_k(const int* __restrict__ cnt, int* __restrict__ row_ptr, int n) {
    __shared__ int part[1024];
    int tid = threadIdx.x;
    int per = (n + 1023) >> 10;
    int base = tid * per;
    int s = 0;
    for (int j = 0; j < per; ++j) {
        int idx = base + j;
        if (idx < n) s += cnt[idx];
    }
    part[tid] = s;
    __syncthreads();
    for (int off = 1; off < 1024; off <<= 1) {
        int v = 0;
        if (tid >= off) v = part[tid - off];
        __syncthreads();
        if (tid >= off) part[tid] += v;
        __syncthreads();
    }
    int run = (tid > 0) ? part[tid - 1] : 0;
    for (int j = 0; j < per; ++j) {
        int idx = base + j;
        if (idx < n) { row_ptr[idx] = run; run += cnt[idx]; }
    }
    if (tid == 0) row_ptr[n] = part[1023];
}

__global__ __launch_bounds__(256) void scatter_k(const int* __restrict__ src, const int* __restrict__ dst,
                                                 const int* __restrict__ row_ptr, int* __restrict__ fill,
                                                 int* __restrict__ col, int E, int n) {
    int e = blockIdx.x * 256 + threadIdx.x;
    if (e < E + n) {
        int s, d;
        if (e < E) { s = src[e]; d = dst[e]; }
        else       { s = d = e - E; }
        int pos = row_ptr[d] + atomicAdd(&fill[d], 1);
        col[pos] = s;
    }
}

// ---------------- input split kernels (fp32 -> bf16 hi/lo, K-padded) -------

__global__ __launch_bounds__(256) void xsplit_k(const float* __restrict__ in,
                                                u16* __restrict__ hi, u16* __restrict__ lo,
                                                int M, int K, int Kp) {
    int idx = blockIdx.x * 256 + threadIdx.x;
    if (idx >= M * Kp) return;
    int m = idx / Kp, k = idx - m * Kp;
    float v = (k < K) ? in[(size_t)m * K + k] : 0.f;
    u16 h = f2bf(v);
    hi[idx] = h;
    lo[idx] = f2bf(v - bf2f(h));
}

// W is [K][N] row-major; produce transposed padded Wt[nn][k], nn<Npad, k<Kp
__global__ __launch_bounds__(256) void wsplit_k(const float* __restrict__ W,
                                                u16* __restrict__ hi, u16* __restrict__ lo,
                                                int K, int N, int Npad, int Kp) {
    int idx = blockIdx.x * 256 + threadIdx.x;
    if (idx >= Npad * Kp) return;
    int nn = idx / Kp, k = idx - nn * Kp;
    float v = (nn < N && k < K) ? W[(size_t)k * N + nn] : 0.f;
    u16 h = f2bf(v);
    hi[idx] = h;
    lo[idx] = f2bf(v - bf2f(h));
}

// ---------------- MFMA split GEMM: C[M,Ncols] = A[M,Kp] @ Wt[N,Kp]^T -------
// Tile 128x128, BK=32. 4 waves (2m x 2n), 64x64 per wave. 3 MFMAs per pair.
// FH>0: fused alpha epilogue (requires C==64, BN=128 -> 2 heads per block).

__device__ __forceinline__ int swz(int r, int s) {
    return (r << 2) | ((s ^ (r & 3) ^ ((r >> 2) & 3)) & 3);
}

template <int FH>
__global__ __launch_bounds__(256) void gemm2(
    const u16* __restrict__ Ahi, const u16* __restrict__ Alo,
    const u16* __restrict__ Bhi, const u16* __restrict__ Blo,
    float* __restrict__ C, const float* __restrict__ aS, const float* __restrict__ aD,
    float* __restrict__ oS, float* __restrict__ oD,
    int M, int Ncols, int Kp)
{
    __shared__ __align__(16) u16 sAh[128 * 32];
    __shared__ __align__(16) u16 sAl[128 * 32];
    __shared__ __align__(16) u16 sBh[128 * 32];
    __shared__ __align__(16) u16 sBl[128 * 32];
    const int tid = threadIdx.x;
    const int m0 = blockIdx.y * 128;
    const int n0 = blockIdx.x * 128;
    const int lane = tid & 63, wave = tid >> 6;
    const int wm = wave >> 1, wn = wave & 1;
    const int l15 = lane & 15, lg = lane >> 4;
    // staging chunk ids: c = tid, tid+256 ; r = c>>2, slot = c&3
    const int r0 = tid >> 2, s0 = tid & 3;
    const int r1 = (tid + 256) >> 2, s1 = tid & 3;
    const int w0 = swz(r0, s0), w1 = swz(r1, s1);
    f32x4 acc[4][4] = {};

    for (int k0 = 0; k0 < Kp; k0 += 32) {
        size_t gA0 = (size_t)(m0 + r0) * Kp + k0 + s0 * 8;
        size_t gA1 = (size_t)(m0 + r1) * Kp + k0 + s1 * 8;
        size_t gB0 = (size_t)(n0 + r0) * Kp + k0 + s0 * 8;
        size_t gB1 = (size_t)(n0 + r1) * Kp + k0 + s1 * 8;
        short8v ah0 = *(const short8v*)(Ahi + gA0);
        short8v ah1 = *(const short8v*)(Ahi + gA1);
        short8v al0 = *(const short8v*)(Alo + gA0);
        short8v al1 = *(const short8v*)(Alo + gA1);
        short8v bh0 = *(const short8v*)(Bhi + gB0);
        short8v bh1 = *(const short8v*)(Bhi + gB1);
        short8v bl0 = *(const short8v*)(Blo + gB0);
        short8v bl1 = *(const short8v*)(Blo + gB1);
        __syncthreads();
        ((short8v*)sAh)[w0] = ah0; ((short8v*)sAh)[w1] = ah1;
        ((short8v*)sAl)[w0] = al0; ((short8v*)sAl)[w1] = al1;
        ((short8v*)sBh)[w0] = bh0; ((short8v*)sBh)[w1] = bh1;
        ((short8v*)sBl)[w0] = bl0; ((short8v*)sBl)[w1] = bl1;
        __syncthreads();
        FragU fah[4], fal[4], fbh[4], fbl[4];
        #pragma unroll
        for (int mf = 0; mf < 4; ++mf) {
            int rr = wm * 64 + mf * 16 + l15;
            int idx = swz(rr, lg);
            fah[mf].s = ((const short8v*)sAh)[idx];
            fal[mf].s = ((const short8v*)sAl)[idx];
        }
        #pragma unroll
        for (int nf = 0; nf < 4; ++nf) {
            int rr = wn * 64 + nf * 16 + l15;
            int idx = swz(rr, lg);
            fbh[nf].s = ((const short8v*)sBh)[idx];
            fbl[nf].s = ((const short8v*)sBl)[idx];
        }
        #pragma unroll
        for (int mf = 0; mf < 4; ++mf) {
            #pragma unroll
            for (int nf = 0; nf < 4; ++nf) {
                acc[mf][nf] = __builtin_amdgcn_mfma_f32_16x16x32_bf16(fah[mf].b, fbh[nf].b, acc[mf][nf], 0, 0, 0);
                acc[mf][nf] = __builtin_amdgcn_mfma_f32_16x16x32_bf16(fah[mf].b, fbl[nf].b, acc[mf][nf], 0, 0, 0);
                acc[mf][nf] = __builtin_amdgcn_mfma_f32_16x16x32_bf16(fal[mf].b, fbh[nf].b, acc[mf][nf], 0, 0, 0);
            }
        }
    }
    // C store: col = n0 + wn*64 + nf*16 + l15 ; row = m0 + wm*64 + mf*16 + lg*4 + r
    #pragma unroll
    for (int mf = 0; mf < 4; ++mf) {
        #pragma unroll
        for (int nf = 0; nf < 4; ++nf) {
            int colg = n0 + wn * 64 + nf * 16 + l15;
            if (colg >= Ncols) continue;
            #pragma unroll
            for (int r = 0; r < 4; ++r) {
                int rowg = m0 + wm * 64 + mf * 16 + lg * 4 + r;
                if (rowg < M) C[(size_t)rowg * Ncols + colg] = acc[mf][nf][r];
            }
        }
    }
    if constexpr (FH > 0) {
        // all cols of wave wn belong to head hh = bx*2 + wn (C==64)
        const int hh = blockIdx.x * 2 + wn;
        const int hcl = (hh < FH) ? hh : (FH - 1);
        float asv[4], adv[4];
        #pragma unroll
        for (int nf = 0; nf < 4; ++nf) {
            int cc = nf * 16 + l15;
            asv[nf] = aS[hcl * 64 + cc];
            adv[nf] = aD[hcl * 64 + cc];
        }
        #pragma unroll
        for (int mf = 0; mf < 4; ++mf) {
            #pragma unroll
            for (int r = 0; r < 4; ++r) {
                float ps = 0.f, pd = 0.f;
                #pragma unroll
                for (int nf = 0; nf < 4; ++nf) {
                    ps += acc[mf][nf][r] * asv[nf];
                    pd += acc[mf][nf][r] * adv[nf];
                }
                #pragma unroll
                for (int off = 1; off < 16; off <<= 1) {
                    ps += __shfl_xor(ps, off);
                    pd += __shfl_xor(pd, off);
                }
                int rowg = m0 + wm * 64 + mf * 16 + lg * 4 + r;
                if (l15 == 0 && hh < FH && rowg < M) {
                    oS[(size_t)rowg * 8 + hh] = ps;
                    oD[(size_t)rowg * 8 + hh] = pd;
                }
            }
        }
    }
}

// ---------------- per-(node,head) attention logits (layer 3 only) ----------

template <int H, int C>
__global__ __launch_bounds__(64) void alphas_k(const float* __restrict__ hf,
                                               const float* __restrict__ a_s,
                                               const float* __restrict__ a_d,
                                               float* __restrict__ out_s,
                                               float* __restrict__ out_d, int n) {
    int i = blockIdx.x;
    if (i >= n) return;
    int lane = threadIdx.x;
    const float* row = hf + (size_t)i * (H * C);
    #pragma unroll
    for (int hh = 0; hh < H; ++hh) {
        float v = 0.f, ws = 0.f, wd = 0.f;
        if (lane < C) {
            v  = row[hh * C + lane];
            ws = a_s[hh * C + lane];
            wd = a_d[hh * C + lane];
        }
        float ps = v * ws, pd = v * wd;
        #pragma unroll
        for (int off = 32; off; off >>= 1) {
            ps += __shfl_xor(ps, off);
            pd += __shfl_xor(pd, off);
        }
        if (lane == 0) {
            out_s[(size_t)i * 8 + hh] = ps;
            out_d[(size_t)i * 8 + hh] = pd;
        }
    }
}

// ---------------- chunked edge softmax + aggregate ----------------
// grid (ceil(n/4), NCH): wave w of block handles node blockIdx.x*4+w, chunk
// blockIdx.y (slow axis -> all nodes of a chunk run together: h-slice stays
// cache-resident). Lane owns 2 channels (float2). No LDS, no barriers.

template <int H, int C, int CPB, bool RELU, bool SPLIT>
__global__ __launch_bounds__(256) void gat_agg3(
    const float* __restrict__ hfeat, const float* __restrict__ as_,
    const float* __restrict__ ad_, const float* __restrict__ bias,
    const int* __restrict__ row_ptr, const int* __restrict__ col,
    float* __restrict__ outf, u16* __restrict__ ohi, u16* __restrict__ olo, int n)
{
    constexpr int HC = H * C;
    const int wv = threadIdx.x >> 6, lane = threadIdx.x & 63;
    const int i = blockIdx.x * 4 + wv;
    if (i >= n) return;
    const int cb = blockIdx.y * CPB;
    const int ch = cb + lane * 2;
    const bool act = (lane * 2 < CPB) && (ch < HC);
    const int h = act ? (ch / C) : 0;
    const int cinh = act ? (ch % C) : 0;
    const int beg = row_ptr[i], end = row_ptr[i + 1];
    float a0 = 0.f, a1 = 0.f, dp = 0.f;
    if (act) {
        const float adh = ad_[(size_t)i * 8 + h];
        const bool lead = (cinh == 0);
        int e = beg;
        for (; e + 2 <= end; e += 2) {
            int sA = col[e], sB = col[e + 1];
            float fA = as_[(size_t)sA * 8 + h] + adh;
            float fB = as_[(size_t)sB * 8 + h] + adh;
            float2 hA = *(const float2*)(hfeat + (size_t)sA * HC + ch);
            float2 hB = *(const float2*)(hfeat + (size_t)sB * HC + ch);
            fA = fA > 0.f ? fA : 0.2f * fA;
            fB = fB > 0.f ? fB : 0.2f * fB;
            float wA = __expf(fA), wB = __expf(fB);
            a0 += wA * hA.x + wB * hB.x;
            a1 += wA * hA.y + wB * hB.y;
            if (lead) dp += wA + wB;
        }
        if (e < end) {
            int sA = col[e];
            float fA = as_[(size_t)sA * 8 + h] + adh;
            float2 hA = *(const float2*)(hfeat + (size_t)sA * HC + ch);
            fA = fA > 0.f ? fA : 0.2f * fA;
            float wA = __expf(fA);
            a0 += wA * hA.x;
            a1 += wA * hA.y;
            if (lead) dp += wA;
        }
    }
    const float den = __shfl(dp, lane - (cinh >> 1)) + 1e-16f;
    if (act) {
        float o0 = a0 / den + bias[ch];
        float o1 = a1 / den + bias[ch + 1];
        if (RELU) { o0 = fmaxf(o0, 0.f); o1 = fmaxf(o1, 0.f); }
        size_t base = (size_t)i * HC + ch;
        if constexpr (SPLIT) {
            ushort2 ph, pl;
            ph.x = f2bf(o0); pl.x = f2bf(o0 - bf2f(ph.x));
            ph.y = f2bf(o1); pl.y = f2bf(o1 - bf2f(ph.y));
            *(ushort2*)(ohi + base) = ph;
            *(ushort2*)(olo + base) = pl;
        } else {
            float2 v; v.x = o0; v.y = o1;
            *(float2*)(outf + base) = v;
        }
    }
}

// ---------------------------------------------------------------------------

extern "C" void kernel_launch(void* const* d_in, const int* in_sizes, int n_in,
                              void* d_out, int out_size, void* d_ws, size_t ws_size,
                              hipStream_t stream) {
    const float* x   = (const float*)d_in[0];
    const int*   ei  = (const int*)d_in[1];
    const float* W1  = (const float*)d_in[2];
    const float* a1s = (const float*)d_in[3];
    const float* a1d = (const float*)d_in[4];
    const float* b1  = (const float*)d_in[5];
    const float* W2  = (const float*)d_in[6];
    const float* a2s = (const float*)d_in[7];
    const float* a2d = (const float*)d_in[8];
    const float* b2  = (const float*)d_in[9];
    const float* W3  = (const float*)d_in[10];
    const float* a3s = (const float*)d_in[11];
    const float* a3d = (const float*)d_in[12];
    const float* b3  = (const float*)d_in[13];
    float* out = (float*)d_out;

    const int Nn = in_sizes[0] / NFEAT;   // 30000
    const int E  = in_sizes[1] / 2;       // 480000
    const int* srcp = ei;
    const int* dstp = ei + E;

    char* ws = (char*)d_ws;
    size_t off = 0;
    auto carve = [&](size_t bytes) -> char* {
        char* p = ws + off;
        off += (bytes + 255) & ~(size_t)255;
        return p;
    };
    float* hbuf = (float*)carve((size_t)Nn * 448 * 4);
    u16*   Xhi  = (u16*)  carve((size_t)MPAD * 448 * 2);
    u16*   Xlo  = (u16*)  carve((size_t)MPAD * 448 * 2);
    u16*   Wthi = (u16*)  carve((size_t)512 * 448 * 2);
    u16*   Wtlo = (u16*)  carve((size_t)512 * 448 * 2);
    float* asb  = (float*)carve((size_t)Nn * 8 * 4);
    float* adb  = (float*)carve((size_t)Nn * 8 * 4);
    int* row_ptr= (int*)  carve((size_t)(Nn + 1) * 4);
    int*   cnt  = (int*)  carve((size_t)Nn * 4);
    int*   col  = (int*)  carve((size_t)(E + Nn) * 4);
    (void)ws_size;

    const int mgrid = MPAD / 128;   // 235
    const int nag = (Nn + 3) / 4;   // 7500

    // ---- build dst-CSR (with self loops) ----
    init_cnt_k<<<(Nn + 255) / 256, 256, 0, stream>>>(cnt, Nn);
    hist_k<<<(E + 255) / 256, 256, 0, stream>>>(dstp, cnt, E);
    scan_k<<<1, 1024, 0, stream>>>(cnt, row_ptr, Nn);
    hipMemsetAsync(cnt, 0, (size_t)Nn * 4, stream);
    scatter_k<<<(E + Nn + 255) / 256, 256, 0, stream>>>(srcp, dstp, row_ptr, cnt, col, E, Nn);

    // ---- layer 1: 129 -> 7x64  (Kp=160, Npad=512) ----
    xsplit_k<<<((Nn * 160) + 255) / 256, 256, 0, stream>>>(x, Xhi, Xlo, Nn, NFEAT, 160);
    wsplit_k<<<((512 * 160) + 255) / 256, 256, 0, stream>>>(W1, Wthi, Wtlo, NFEAT, 448, 512, 160);
    gemm2<7><<<dim3(4, mgrid), 256, 0, stream>>>(Xhi, Xlo, Wthi, Wtlo, hbuf,
                                                 a1s, a1d, asb, adb, Nn, 448, 160);
    gat_agg3<7, 64, 128, true, true><<<dim3(nag, 4), 256, 0, stream>>>(
        hbuf, asb, adb, b1, row_ptr, col, nullptr, Xhi, Xlo, Nn);

    // ---- layer 2: 448 -> 6x64  (Kp=448, Npad=384) ----
    wsplit_k<<<((384 * 448) + 255) / 256, 256, 0, stream>>>(W2, Wthi, Wtlo, 448, 384, 384, 448);
    gemm2<6><<<dim3(3, mgrid), 256, 0, stream>>>(Xhi, Xlo, Wthi, Wtlo, hbuf,
                                                 a2s, a2d, asb, adb, Nn, 384, 448);
    gat_agg3<6, 64, 128, true, true><<<dim3(nag, 3), 256, 0, stream>>>(
        hbuf, asb, adb, b2, row_ptr, col, nullptr, Xhi, Xlo, Nn);

    // ---- layer 3: 384 -> 6x40  (Kp=384, Npad=256) ----
    wsplit_k<<<((256 * 384) + 255) / 256, 256, 0, stream>>>(W3, Wthi, Wtlo, 384, 240, 256, 384);
    gemm2<0><<<dim3(2, mgrid), 256, 0, stream>>>(Xhi, Xlo, Wthi, Wtlo, hbuf,
                                                 nullptr, nullptr, nullptr, nullptr, Nn, 240, 384);
    alphas_k<6, 40><<<Nn, 64, 0, stream>>>(hbuf, a3s, a3d, asb, adb, Nn);
    gat_agg3<6, 40, 120, false, false><<<dim3(nag, 2), 256, 0, stream>>>(
        hbuf, asb, adb, b3, row_ptr, col, out, nullptr, nullptr, Nn);
}